// Round 1
// 178.281 us; speedup vs baseline: 1.0190x; 1.0190x over previous
//
#include <hip/hip_runtime.h>
#include <cmath>

#define QN    65536
#define KVN   65536
#define CD    256
#define NH    8
#define NE    524288
#define SCL   0.0625f      // 1/sqrt(256)
#define LNEPS 1e-5f
#define LOG2E 1.4426950408889634f

typedef __bf16 bf16x8 __attribute__((ext_vector_type(8)));
typedef float  f32x4  __attribute__((ext_vector_type(4)));

__device__ __forceinline__ float b2f(ushort u) {
    return __builtin_bit_cast(float, (unsigned)u << 16);
}
__device__ __forceinline__ ushort f2bf(float f) {
    unsigned u = __builtin_bit_cast(unsigned, f);
    return (ushort)((u + 0x7FFFu + ((u >> 16) & 1u)) >> 16);   // RNE
}

#if __has_builtin(__builtin_amdgcn_exp2f)
__device__ __forceinline__ float fexp2(float x) { return __builtin_amdgcn_exp2f(x); }
#else
__device__ __forceinline__ float fexp2(float x) {
    float r; asm volatile("v_exp_f32 %0, %1" : "=v"(r) : "v"(x)); return r;
}
#endif

#define GLD16(g, l) __builtin_amdgcn_global_load_lds( \
    (const __attribute__((address_space(1))) unsigned int*)(const void*)(g), \
    (__attribute__((address_space(3))) unsigned int*)(void*)(l), 16, 0, 0)

// ---------------------------------------------------------------- fused prep:
// blk [0, LNB):        LN(q) -> bf16 qn           (4 rows/block)
// blk [LNB, LNB+192):  wq|wk|wo fp32 -> bf16      (1024 els/block)
// blk [.., +NE/256):   CSR row_lo fill
#define LNB   (QN / 4)
#define RLB   (NE / 256)
__global__ __launch_bounds__(256) void prep_k(const float* __restrict__ q,
                                              const float* __restrict__ lnw,
                                              const float* __restrict__ lnb,
                                              const float* __restrict__ wq,
                                              const float* __restrict__ wk,
                                              const float* __restrict__ wo,
                                              const int* __restrict__ dst,
                                              ushort* __restrict__ qn,
                                              ushort* __restrict__ wb,
                                              int* __restrict__ row_lo) {
    const int blk = blockIdx.x;
    if (blk < LNB) {
        int row  = (blk << 2) + (threadIdx.x >> 6);
        int lane = threadIdx.x & 63;
        float4 v = *(const float4*)(q + (size_t)row * CD + (lane << 2));
        float s  = v.x + v.y + v.z + v.w;
        float s2 = v.x * v.x + v.y * v.y + v.z * v.z + v.w * v.w;
        #pragma unroll
        for (int m = 1; m < 64; m <<= 1) {
            s  += __shfl_xor(s, m);
            s2 += __shfl_xor(s2, m);
        }
        float mu   = s * (1.0f / CD);
        float rstd = rsqrtf(s2 * (1.0f / CD) - mu * mu + LNEPS);
        float4 w = *(const float4*)(lnw + (lane << 2));
        float4 b = *(const float4*)(lnb + (lane << 2));
        ushort4 o;
        o.x = f2bf((v.x - mu) * rstd * w.x + b.x);
        o.y = f2bf((v.y - mu) * rstd * w.y + b.y);
        o.z = f2bf((v.z - mu) * rstd * w.z + b.z);
        o.w = f2bf((v.w - mu) * rstd * w.w + b.w);
        *(ushort4*)(qn + (size_t)row * CD + (lane << 2)) = o;
    } else if (blk < LNB + 192) {
        int idx4 = ((blk - LNB) * 256 + threadIdx.x) * 4;   // 0 .. 3*65536
        int mat  = idx4 >> 16;
        int off  = idx4 & 65535;
        const float* src = (mat == 0) ? wq : (mat == 1) ? wk : wo;
        float4 v = *(const float4*)(src + off);
        ushort4 o;
        o.x = f2bf(v.x); o.y = f2bf(v.y); o.z = f2bf(v.z); o.w = f2bf(v.w);
        *(ushort4*)(wb + idx4) = o;
    } else {
        int e = (blk - LNB - 192) * 256 + threadIdx.x;
        int d     = dst[e];
        int dprev = (e == 0) ? -1 : dst[e - 1];
        for (int qq = dprev + 1; qq <= d; ++qq) row_lo[qq] = e;
        if (e == NE - 1)
            for (int qq = d + 1; qq <= QN; ++qq) row_lo[qq] = NE;
    }
}

// ---------------------------------------------------------------- bf16 MFMA GEMM
// 128x128 tile, BK=32, 4 waves (2x2), K=256 -> 8 kt iterations.
// v3: 4-slot LDS ring (64KB, 2 blocks/CU), stage-ahead-3 via global_load_lds,
// COUNTED s_waitcnt vmcnt(N) + raw s_barrier (never drains the prefetch queue
// in the main loop; N reaches 0 only at kt=7). This removes the per-kt
// vmcnt(0) barrier drain that left the kernel latency-bound at 2.4 TB/s.
// blockIdx.z==0: A = A0 (bf16, global_load_lds, 4 GLD16/slot incl. B).
// blockIdx.z==1: A = Afp (fp32) register-staged 1-ahead: loads issued at loop
//                top (OLDEST, so the compiler's wait at the convert point is
//                vmcnt(2), keeping B prefetch alive), convert + ds_write after
//                the MFMA block.
// EPI 0: bf16 out.  EPI 1: f32 out + resid.
template<int EPI>
__global__ __launch_bounds__(256) void gemm_bf16_k(const ushort* __restrict__ A0,
                                                   const float* __restrict__ Afp,
                                                   const ushort* __restrict__ B0,
                                                   const ushort* __restrict__ B1,
                                                   const float* __restrict__ bias0,
                                                   const float* __restrict__ bias1,
                                                   const float* __restrict__ resid,
                                                   void* __restrict__ C0,
                                                   void* __restrict__ C1) {
    const bool conv = (blockIdx.z != 0);
    const ushort* B    = conv ? B1 : B0;
    const float*  bias = conv ? bias1 : bias0;
    void*         Cout = conv ? C1 : C0;

    __shared__ __align__(16) ushort As[4][128 * 32];   // 32 KB ring
    __shared__ __align__(16) ushort Bs[4][128 * 32];   // 32 KB ring
    const int t    = threadIdx.x;
    const int lane = t & 63;
    const int wid  = t >> 6;
    const int wm   = wid & 1, wn = wid >> 1;
    const size_t bm = (size_t)blockIdx.x * 128;
    const size_t bn = (size_t)blockIdx.y * 128;

    const int sr = t >> 2;          // 0..63 staging row (first half)
    const int sc = (t & 3) * 8;     // staging col (8 elems = 16B)

    f32x4 acc[4][4] = {};

    // ---- prologue: issue slots 0..2 (3-deep prefetch), conv writes A slot 0
    if (conv) {
        const float* ga = Afp + (bm + sr) * CD + sc;   // A loads FIRST (oldest)
        float4 a0 = *(const float4*)(ga);
        float4 a1 = *(const float4*)(ga + 4);
        float4 a2 = *(const float4*)(ga + 64 * CD);
        float4 a3 = *(const float4*)(ga + 64 * CD + 4);
        #pragma unroll
        for (int s = 0; s < 3; ++s) {
            const ushort* gb = B + (bn + sr) * CD + s * 32 + sc;
            GLD16(gb,           &Bs[s][wid * 512]);
            GLD16(gb + 64 * CD, &Bs[s][2048 + wid * 512]);
        }
        union { ushort u[8]; uint4 v; } p0, p1;
        p0.u[0] = f2bf(a0.x); p0.u[1] = f2bf(a0.y); p0.u[2] = f2bf(a0.z); p0.u[3] = f2bf(a0.w);
        p0.u[4] = f2bf(a1.x); p0.u[5] = f2bf(a1.y); p0.u[6] = f2bf(a1.z); p0.u[7] = f2bf(a1.w);
        p1.u[0] = f2bf(a2.x); p1.u[1] = f2bf(a2.y); p1.u[2] = f2bf(a2.z); p1.u[3] = f2bf(a2.w);
        p1.u[4] = f2bf(a3.x); p1.u[5] = f2bf(a3.y); p1.u[6] = f2bf(a3.z); p1.u[7] = f2bf(a3.w);
        *(uint4*)&As[0][sr * 32 + sc]        = p0.v;
        *(uint4*)&As[0][(sr + 64) * 32 + sc] = p1.v;
    } else {
        #pragma unroll
        for (int s = 0; s < 3; ++s) {
            const ushort* gb = B  + (bn + sr) * CD + s * 32 + sc;
            const ushort* ga = A0 + (bm + sr) * CD + s * 32 + sc;
            GLD16(gb,           &Bs[s][wid * 512]);
            GLD16(gb + 64 * CD, &Bs[s][2048 + wid * 512]);
            GLD16(ga,           &As[s][wid * 512]);
            GLD16(ga + 64 * CD, &As[s][2048 + wid * 512]);
        }
    }
    // no full barrier here: ITER(0)'s counted-wait barrier is the first sync.

    // iteration KT: stage slot KT+3, wait until slot KT landed (vmcnt leaves
    // younger slots in flight), barrier, compute, read-done barrier (no vm drain).
#define ITER(KT, VMZ0, VMZ1)                                                          \
  {                                                                                   \
    float4 a0n, a1n, a2n, a3n;                                                        \
    if (conv) {                                                                       \
      if ((KT) < 7) {                                                                 \
        const float* ga = Afp + (bm + sr) * CD + ((KT) + 1) * 32 + sc;                \
        a0n = *(const float4*)(ga);                                                   \
        a1n = *(const float4*)(ga + 4);                                               \
        a2n = *(const float4*)(ga + 64 * CD);                                         \
        a3n = *(const float4*)(ga + 64 * CD + 4);                                     \
      }                                                                               \
      if ((KT) + 3 <= 7) {                                                            \
        const ushort* gb = B + (bn + sr) * CD + ((KT) + 3) * 32 + sc;                 \
        GLD16(gb,           &Bs[((KT) + 3) & 3][wid * 512]);                          \
        GLD16(gb + 64 * CD, &Bs[((KT) + 3) & 3][2048 + wid * 512]);                   \
      }                                                                               \
      asm volatile("s_waitcnt vmcnt(" #VMZ1 ") lgkmcnt(0)\ns_barrier" ::: "memory");  \
    } else {                                                                          \
      if ((KT) + 3 <= 7) {                                                            \
        const ushort* gb = B  + (bn + sr) * CD + ((KT) + 3) * 32 + sc;                \
        const ushort* ga = A0 + (bm + sr) * CD + ((KT) + 3) * 32 + sc;                \
        GLD16(gb,           &Bs[((KT) + 3) & 3][wid * 512]);                          \
        GLD16(gb + 64 * CD, &Bs[((KT) + 3) & 3][2048 + wid * 512]);                   \
        GLD16(ga,           &As[((KT) + 3) & 3][wid * 512]);                          \
        GLD16(ga + 64 * CD, &As[((KT) + 3) & 3][2048 + wid * 512]);                   \
      }                                                                               \
      asm volatile("s_waitcnt vmcnt(" #VMZ0 ") lgkmcnt(0)\ns_barrier" ::: "memory");  \
    }                                                                                 \
    {                                                                                 \
      const int kq = (lane >> 4) * 8;                                                 \
      bf16x8 af[4], bg[4];                                                            \
      _Pragma("unroll")                                                               \
      for (int mi = 0; mi < 4; ++mi)                                                  \
        af[mi] = *(const bf16x8*)&As[(KT) & 3][(wm * 64 + mi * 16 + (lane & 15)) * 32 + kq]; \
      _Pragma("unroll")                                                               \
      for (int ni = 0; ni < 4; ++ni)                                                  \
        bg[ni] = *(const bf16x8*)&Bs[(KT) & 3][(wn * 64 + ni * 16 + (lane & 15)) * 32 + kq]; \
      _Pragma("unroll")                                                               \
      for (int mi = 0; mi < 4; ++mi)                                                  \
        _Pragma("unroll")                                                             \
        for (int ni = 0; ni < 4; ++ni)                                                \
          acc[mi][ni] = __builtin_amdgcn_mfma_f32_16x16x32_bf16(af[mi], bg[ni], acc[mi][ni], 0, 0, 0); \
    }                                                                                 \
    if (conv && (KT) < 7) {      /* convert+write AFTER MFMA: latency hidden */       \
      union { ushort u[8]; uint4 v; } p0, p1;                                         \
      p0.u[0] = f2bf(a0n.x); p0.u[1] = f2bf(a0n.y); p0.u[2] = f2bf(a0n.z); p0.u[3] = f2bf(a0n.w); \
      p0.u[4] = f2bf(a1n.x); p0.u[5] = f2bf(a1n.y); p0.u[6] = f2bf(a1n.z); p0.u[7] = f2bf(a1n.w); \
      p1.u[0] = f2bf(a2n.x); p1.u[1] = f2bf(a2n.y); p1.u[2] = f2bf(a2n.z); p1.u[3] = f2bf(a2n.w); \
      p1.u[4] = f2bf(a3n.x); p1.u[5] = f2bf(a3n.y); p1.u[6] = f2bf(a3n.z); p1.u[7] = f2bf(a3n.w); \
      *(uint4*)&As[((KT) + 1) & 3][sr * 32 + sc]        = p0.v;                       \
      *(uint4*)&As[((KT) + 1) & 3][(sr + 64) * 32 + sc] = p1.v;                       \
    }                                                                                 \
    asm volatile("s_waitcnt lgkmcnt(0)\ns_barrier" ::: "memory");                     \
  }

    // vmcnt math, z0 (4 GLD16/slot): outstanding after stage at KT<=4 is 16,
    // slot KT done when <=12 remain; tail 8/4/0.
    // z1 (2 B-GLD16/slot + 4 fp32 A loads, A issued oldest each iter):
    // younger-than-B(KT) = B(KT+1..KT+3) + A(KT+1) -> 10; tail 8/6/0.
    ITER(0, 12, 10)
    ITER(1, 12, 10)
    ITER(2, 12, 10)
    ITER(3, 12, 10)
    ITER(4, 12, 10)
    ITER(5,  8,  8)
    ITER(6,  4,  6)
    ITER(7,  0,  0)
#undef ITER

    const int col0 = lane & 15;
    #pragma unroll
    for (int ni = 0; ni < 4; ++ni) {
        const size_t col = bn + wn * 64 + ni * 16 + col0;
        const float bv = bias[col];
        #pragma unroll
        for (int mi = 0; mi < 4; ++mi) {
            #pragma unroll
            for (int r = 0; r < 4; ++r) {
                const size_t row = bm + wm * 64 + mi * 16 + (lane >> 4) * 4 + r;
                float v = acc[mi][ni][r] + bv;
                if (EPI == 0) {
                    ((ushort*)Cout)[row * CD + col] = f2bf(v);
                } else {
                    ((float*)Cout)[row * CD + col] = v + resid[row * CD + col];
                }
            }
        }
    }
}

// ---------------------------------------------------------------- edge attention
// R15 kernel, byte-identical (proven; compiler software-pipelines the
// chunk loop; 1-wave blocks retire independently; deg<=16 weights in-register).
__global__ __launch_bounds__(64) void edge_attn_k(const ushort* __restrict__ qp,
                                                  const ushort* __restrict__ kp,
                                                  const float* __restrict__ bias,
                                                  const int* __restrict__ src,
                                                  const int* __restrict__ row_lo,
                                                  ushort* __restrict__ ao,
                                                  float* __restrict__ simw) {
    const int q    = blockIdx.x;
    const int lane = threadIdx.x;
    const int lo = row_lo[q];
    const int hi = row_lo[q + 1];
    const int deg = hi - lo;
    const float SC2 = SCL * LOG2E;

    ushort4 qu = *(const ushort4*)(qp + (size_t)q * CD + (lane << 2));
    float4 qv = {b2f(qu.x) * SC2, b2f(qu.y) * SC2, b2f(qu.z) * SC2, b2f(qu.w) * SC2};
    float4 acc = {0.f, 0.f, 0.f, 0.f};
    float m = -INFINITY, s = 0.f;
    float wval0 = 0.f, wval1 = 0.f;      // chunk-0 / chunk-1 transposed sims

    for (int base = lo; base < hi; base += 8) {
        const int cnum = (base - lo) >> 3;
        // ---- load phase: 1 src chunk + 1 bias chunk + up to 8 kp rows
        int sv = 0;
        if (lane < 8 && base + lane < hi) sv = src[base + lane];
        float bch = 0.f;
        if (lane < (hi - base) * 8) bch = bias[(size_t)base * NH + lane] * SC2;
        ushort4 ku[8];
        #pragma unroll
        for (int i = 0; i < 8; ++i) {
            if (base + i < hi) {
                int sidx = __shfl(sv, i);
                ku[i] = *(const ushort4*)(kp + (size_t)sidx * CD + (lane << 2));
            }
        }
        // ---- per-edge compute (online softmax, log2 domain)
        #pragma unroll
        for (int i = 0; i < 8; ++i) {
            if (base + i < hi) {
                float4 kv = {b2f(ku[i].x), b2f(ku[i].y), b2f(ku[i].z), b2f(ku[i].w)};
                float d = qv.x * kv.x + qv.y * kv.y + qv.z * kv.z + qv.w * kv.w;
                d += __shfl_xor(d, 1);
                d += __shfl_xor(d, 2);
                d += __shfl_xor(d, 4);
                float bvi = __shfl(bch, (i << 3) + (lane >> 3));
                float sim = d + bvi;                       // log2 domain
                float tw = __shfl(sim, (lane & 7) << 3);   // capture for weights output
                bool mine = ((lane >> 3) == i);
                if (deg <= 16) {
                    if (cnum == 0) wval0 = mine ? tw : wval0;
                    else           wval1 = mine ? tw : wval1;
                } else {
                    wval0 = mine ? tw : wval0;             // rolling (staged per chunk)
                }
                float mnew  = fmaxf(m, sim);
                float scale = fexp2(m - mnew);             // first edge: exp2(-inf)=0
                float ex    = fexp2(sim - mnew);
                s = s * scale + ex;
                acc.x = acc.x * scale + ex * kv.x;
                acc.y = acc.y * scale + ex * kv.y;
                acc.z = acc.z * scale + ex * kv.z;
                acc.w = acc.w * scale + ex * kv.w;
                m = mnew;
            }
        }
        // ---- stage raw (log2) sims only for deg>16 queries (rare)
        if (deg > 16) {
            int lim = hi - base; if (lim > 8) lim = 8;
            if (lane < lim * 8) simw[(size_t)base * NH + lane] = wval0;
        }
    }

    float ws  = s + 1e-8f;
    float inv = 1.0f / ws;
    ushort4 o;
    o.x = f2bf(acc.x * inv);
    o.y = f2bf(acc.y * inv);
    o.z = f2bf(acc.z * inv);
    o.w = f2bf(acc.w * inv);
    *(ushort4*)(ao + (size_t)q * CD + (lane << 2)) = o;

    if (deg > 0) {
        const float mm = __shfl(m,   (lane & 7) << 3);     // state of head lane&7
        const float ii = __shfl(inv, (lane & 7) << 3);
        if (deg <= 8) {
            if (lane < deg * 8)
                simw[(size_t)lo * NH + lane] = fexp2(wval0 - mm) * ii;
        } else if (deg <= 16) {
            simw[(size_t)lo * NH + lane] = fexp2(wval0 - mm) * ii;          // edges lo..lo+7
            if (lane < (deg - 8) * 8)
                simw[(size_t)(lo + 8) * NH + lane] = fexp2(wval1 - mm) * ii; // edges lo+8..
        } else {
            asm volatile("s_waitcnt vmcnt(0)" ::: "memory");   // drain sim stores
            for (int i = lane; i < deg * 8; i += 64) {
                size_t idx = (size_t)lo * NH + i;          // head = i&7 = lane&7
                float v = simw[idx];
                simw[idx] = fexp2(v - mm) * ii;
            }
        }
    }
}

// ---------------------------------------------------------------- launch
extern "C" void kernel_launch(void* const* d_in, const int* in_sizes, int n_in,
                              void* d_out, int out_size, void* d_ws, size_t ws_size,
                              hipStream_t stream) {
    const float* q    = (const float*)d_in[0];
    const float* k    = (const float*)d_in[1];
    const float* bias = (const float*)d_in[2];
    const float* lnw  = (const float*)d_in[3];
    const float* lnb  = (const float*)d_in[4];
    const float* wq   = (const float*)d_in[5];
    const float* bq   = (const float*)d_in[6];
    const float* wk   = (const float*)d_in[7];
    const float* bk   = (const float*)d_in[8];
    const float* wo   = (const float*)d_in[9];
    const float* bo   = (const float*)d_in[10];
    const int*   src  = (const int*)d_in[11];
    const int*   dst  = (const int*)d_in[12];

    float* out_m = (float*)d_out;                   // [QN][CD] fp32
    float* out_w = out_m + (size_t)QN * CD;         // [NE][NH] fp32 (weights)

    ushort* qn_b = (ushort*)d_ws;                   // [QN][CD]  LN(q) bf16 -> reused as attn_out
    ushort* qp_b = qn_b + (size_t)QN * CD;          // [QN][CD]  qp bf16
    ushort* kp_b = qp_b + (size_t)QN * CD;          // [KVN][CD] kp bf16
    ushort* wb   = kp_b + (size_t)KVN * CD;         // 3 x [256*256] bf16 weights
    int*    rowlo = (int*)(wb + 3 * 65536);         // [QN+1]

    prep_k<<<dim3(LNB + 192 + RLB), dim3(256), 0, stream>>>(
        q, lnw, lnb, wq, wk, wo, dst, qn_b, wb, rowlo);

    // z=0: qp = LN(q)@wq  (bf16 A via global_load_lds)
    // z=1: kp = k@wk      (fp32 A, convert fused into register staging)
    gemm_bf16_k<0><<<dim3(QN / 128, 2, 2), dim3(256), 0, stream>>>(
        qn_b, k, wb, wb + 65536, bq, bk, nullptr, qp_b, kp_b);

    edge_attn_k<<<dim3(QN), dim3(64), 0, stream>>>(
        qp_b, kp_b, bias, src, rowlo, qn_b /*ao*/, out_w);

    gemm_bf16_k<1><<<dim3(QN / 128, 2, 1), dim3(256), 0, stream>>>(
        qn_b, nullptr, wb + 131072, wb + 131072, bo, bo, q, out_m, out_m);
}

// Round 2
// 170.106 us; speedup vs baseline: 1.0679x; 1.0481x over previous
//
#include <hip/hip_runtime.h>
#include <cmath>

#define QN    65536
#define KVN   65536
#define CD    256
#define NH    8
#define NE    524288
#define SCL   0.0625f      // 1/sqrt(256)
#define LNEPS 1e-5f
#define LOG2E 1.4426950408889634f

typedef __bf16 bf16x8 __attribute__((ext_vector_type(8)));
typedef float  f32x4  __attribute__((ext_vector_type(4)));

__device__ __forceinline__ float b2f(ushort u) {
    return __builtin_bit_cast(float, (unsigned)u << 16);
}
__device__ __forceinline__ ushort f2bf(float f) {
    unsigned u = __builtin_bit_cast(unsigned, f);
    return (ushort)((u + 0x7FFFu + ((u >> 16) & 1u)) >> 16);   // RNE
}

#if __has_builtin(__builtin_amdgcn_exp2f)
__device__ __forceinline__ float fexp2(float x) { return __builtin_amdgcn_exp2f(x); }
#else
__device__ __forceinline__ float fexp2(float x) {
    float r; asm volatile("v_exp_f32 %0, %1" : "=v"(r) : "v"(x)); return r;
}
#endif

#define GLD16(g, l) __builtin_amdgcn_global_load_lds( \
    (const __attribute__((address_space(1))) unsigned int*)(const void*)(g), \
    (__attribute__((address_space(3))) unsigned int*)(void*)(l), 16, 0, 0)

// ---------------------------------------------------------------- fused prep:
// blk [0, LNB):          LN(q) -> bf16 qn           (4 rows/block)
// blk [LNB, LNB+192):    wq|wk|wo fp32 -> bf16      (1024 els/block)
// blk [.., +NE/256):     CSR row_lo fill
// blk [.., +LNB):        k fp32 -> bf16 kb          (4 rows/block)  [NEW]
#define LNB   (QN / 4)
#define RLB   (NE / 256)
__global__ __launch_bounds__(256) void prep_k(const float* __restrict__ q,
                                              const float* __restrict__ k,
                                              const float* __restrict__ lnw,
                                              const float* __restrict__ lnb,
                                              const float* __restrict__ wq,
                                              const float* __restrict__ wk,
                                              const float* __restrict__ wo,
                                              const int* __restrict__ dst,
                                              ushort* __restrict__ qn,
                                              ushort* __restrict__ kb,
                                              ushort* __restrict__ wb,
                                              int* __restrict__ row_lo) {
    const int blk = blockIdx.x;
    if (blk < LNB) {
        int row  = (blk << 2) + (threadIdx.x >> 6);
        int lane = threadIdx.x & 63;
        float4 v = *(const float4*)(q + (size_t)row * CD + (lane << 2));
        float s  = v.x + v.y + v.z + v.w;
        float s2 = v.x * v.x + v.y * v.y + v.z * v.z + v.w * v.w;
        #pragma unroll
        for (int m = 1; m < 64; m <<= 1) {
            s  += __shfl_xor(s, m);
            s2 += __shfl_xor(s2, m);
        }
        float mu   = s * (1.0f / CD);
        float rstd = rsqrtf(s2 * (1.0f / CD) - mu * mu + LNEPS);
        float4 w = *(const float4*)(lnw + (lane << 2));
        float4 b = *(const float4*)(lnb + (lane << 2));
        ushort4 o;
        o.x = f2bf((v.x - mu) * rstd * w.x + b.x);
        o.y = f2bf((v.y - mu) * rstd * w.y + b.y);
        o.z = f2bf((v.z - mu) * rstd * w.z + b.z);
        o.w = f2bf((v.w - mu) * rstd * w.w + b.w);
        *(ushort4*)(qn + (size_t)row * CD + (lane << 2)) = o;
    } else if (blk < LNB + 192) {
        int idx4 = ((blk - LNB) * 256 + threadIdx.x) * 4;   // 0 .. 3*65536
        int mat  = idx4 >> 16;
        int off  = idx4 & 65535;
        const float* src = (mat == 0) ? wq : (mat == 1) ? wk : wo;
        float4 v = *(const float4*)(src + off);
        ushort4 o;
        o.x = f2bf(v.x); o.y = f2bf(v.y); o.z = f2bf(v.z); o.w = f2bf(v.w);
        *(ushort4*)(wb + idx4) = o;
    } else if (blk < LNB + 192 + RLB) {
        int e = (blk - LNB - 192) * 256 + threadIdx.x;
        int d     = dst[e];
        int dprev = (e == 0) ? -1 : dst[e - 1];
        for (int qq = dprev + 1; qq <= d; ++qq) row_lo[qq] = e;
        if (e == NE - 1)
            for (int qq = d + 1; qq <= QN; ++qq) row_lo[qq] = NE;
    } else {
        int row  = ((blk - LNB - 192 - RLB) << 2) + (threadIdx.x >> 6);
        int lane = threadIdx.x & 63;
        float4 v = *(const float4*)(k + (size_t)row * CD + (lane << 2));
        ushort4 o;
        o.x = f2bf(v.x); o.y = f2bf(v.y); o.z = f2bf(v.z); o.w = f2bf(v.w);
        *(ushort4*)(kb + (size_t)row * CD + (lane << 2)) = o;
    }
}

// ---------------------------------------------------------------- persistent bf16 GEMM
// One block per CU (LDS 128 KB), 512 threads = 8 waves (2m x 4n), tile 128x128.
// B panel (256x128-col slice of the weight matrix, 64 KB) loaded into LDS ONCE.
// A streamed through an 8-slot LDS ring (8 KB/slot) with stage-ahead-6 and
// counted s_waitcnt vmcnt(N); ONE s_barrier per K-step.  NT row-tiles / block.
// Swapped MFMA operands (mfma(bg, af)) put 4 consecutive C-cols per lane ->
// vectorized epilogue stores (8 store instrs/thread) that keep post-epilogue
// waits counted (vmcnt(6+E)) instead of draining the ring.
// EPI 0: bf16 out (E=8).  EPI 1: f32 out + resid (E=16).
template<int EPI, int NT>
__global__ __launch_bounds__(512) void gemm2_k(const ushort* __restrict__ A0,
                                               const ushort* __restrict__ A1,
                                               const ushort* __restrict__ B0,
                                               const ushort* __restrict__ B1,
                                               const float* __restrict__ bias0,
                                               const float* __restrict__ bias1,
                                               const float* __restrict__ resid,
                                               void* __restrict__ C0,
                                               void* __restrict__ C1) {
    const bool second = (blockIdx.z != 0);
    const ushort* Ap   = second ? A1 : A0;
    const ushort* B    = second ? B1 : B0;
    const float*  bias = second ? bias1 : bias0;
    void*         Cout = second ? C1 : C0;

    __shared__ __align__(16) ushort Bs[8][4096];   // 64 KB: full B panel, 8 k-slices
    __shared__ __align__(16) ushort As[8][4096];   // 64 KB: A ring, 8 slots

    const int t    = threadIdx.x;
    const int lane = t & 63;
    const int wid  = t >> 6;             // 0..7
    const int wm   = wid & 1;            // 2 wave-rows
    const int wn   = wid >> 1;           // 4 wave-cols
    const size_t bn  = (size_t)blockIdx.y * 128;
    size_t bm = (size_t)blockIdx.x * (NT * 128);

    const int sr = t >> 2;               // 0..127 staging row
    const int sc = (t & 3) * 8;          // staging col (8 ushorts = 16 B)

    constexpr int E = (EPI == 0) ? 8 : 16;   // epilogue vmem instrs (stores [+resid loads])

    f32x4 acc[4][2] = {};
    f32x4 biasv[2];
    #pragma unroll
    for (int ni = 0; ni < 2; ++ni)
        biasv[ni] = *(const f32x4*)(bias + bn + wn * 32 + ni * 16 + ((lane >> 4) << 2));

    // ---- prologue: whole B panel + A slots 0..5
    #pragma unroll
    for (int s = 0; s < 8; ++s)
        GLD16(B + (bn + sr) * CD + (s << 5) + sc, &Bs[s][wid << 9]);
    #pragma unroll
    for (int s = 0; s < 6; ++s)
        GLD16(Ap + (bm + sr) * CD + (s << 5) + sc, &As[s][wid << 9]);
    // materialize bias NOW (counted wait vmcnt(14), not a ring-drain at 1st epilogue)
    asm volatile("" : "+v"(biasv[0]), "+v"(biasv[1]));

    // KSTEP: stage slot (KT+6) [tile +1 when KT>=2], counted wait + barrier,
    // then 6 ds_read_b128 + 8 MFMA on slot KT.
#define KSTEP(KT, VM, GUARD)                                                          \
  {                                                                                   \
    if (GUARD) {                                                                      \
      const ushort* ga_ = Ap + (bm + (((KT) >= 2) ? 128 : 0) + sr) * CD               \
                          + ((((KT) + 6) & 7) << 5) + sc;                             \
      GLD16(ga_, &As[((KT) + 6) & 7][wid << 9]);                                      \
    }                                                                                 \
    asm volatile("s_waitcnt vmcnt(%0) lgkmcnt(0)\n\ts_barrier" :: "i"(VM) : "memory");\
    {                                                                                 \
      const int kq_ = (lane >> 4) << 3;                                               \
      bf16x8 af_[4], bg_[2];                                                          \
      _Pragma("unroll")                                                               \
      for (int mi = 0; mi < 4; ++mi)                                                  \
        af_[mi] = *(const bf16x8*)&As[(KT) & 7][((wm * 64 + mi * 16 + (lane & 15)) << 5) + kq_]; \
      _Pragma("unroll")                                                               \
      for (int ni = 0; ni < 2; ++ni)                                                  \
        bg_[ni] = *(const bf16x8*)&Bs[(KT)][((wn * 32 + ni * 16 + (lane & 15)) << 5) + kq_];     \
      _Pragma("unroll")                                                               \
      for (int mi = 0; mi < 4; ++mi)                                                  \
        _Pragma("unroll")                                                             \
        for (int ni = 0; ni < 2; ++ni)                                                \
          acc[mi][ni] = __builtin_amdgcn_mfma_f32_16x16x32_bf16(bg_[ni], af_[mi], acc[mi][ni], 0, 0, 0); \
    }                                                                                 \
  }

    // swapped-operand layout: lane holds row = ..+(lane&15), cols = ..+(lane>>4)*4+r
#define EPILOG()                                                                      \
  {                                                                                   \
    _Pragma("unroll")                                                                 \
    for (int mi = 0; mi < 4; ++mi) {                                                  \
      const size_t row_ = bm + wm * 64 + mi * 16 + (lane & 15);                       \
      _Pragma("unroll")                                                               \
      for (int ni = 0; ni < 2; ++ni) {                                                \
        const size_t col_ = bn + wn * 32 + ni * 16 + ((lane >> 4) << 2);              \
        if (EPI == 0) {                                                               \
          ushort4 o_;                                                                 \
          o_.x = f2bf(acc[mi][ni][0] + biasv[ni][0]);                                 \
          o_.y = f2bf(acc[mi][ni][1] + biasv[ni][1]);                                 \
          o_.z = f2bf(acc[mi][ni][2] + biasv[ni][2]);                                 \
          o_.w = f2bf(acc[mi][ni][3] + biasv[ni][3]);                                 \
          *(ushort4*)((ushort*)Cout + row_ * CD + col_) = o_;                         \
        } else {                                                                      \
          f32x4 rs_ = *(const f32x4*)(resid + row_ * CD + col_);                      \
          f32x4 o_;                                                                   \
          o_[0] = acc[mi][ni][0] + biasv[ni][0] + rs_[0];                             \
          o_[1] = acc[mi][ni][1] + biasv[ni][1] + rs_[1];                             \
          o_[2] = acc[mi][ni][2] + biasv[ni][2] + rs_[2];                             \
          o_[3] = acc[mi][ni][3] + biasv[ni][3] + rs_[3];                             \
          *(f32x4*)((float*)Cout + row_ * CD + col_) = o_;                            \
        }                                                                             \
        acc[mi][ni] = (f32x4){0.f, 0.f, 0.f, 0.f};                                    \
      }                                                                               \
    }                                                                                 \
    asm volatile("" ::: "memory");  /* keep stores before next tile's stage */        \
  }

    // ---- tile 0 (no prior stores in flight): steady vmcnt(6)
    KSTEP(0, 6, 1) KSTEP(1, 6, 1) KSTEP(2, 6, 1) KSTEP(3, 6, 1)
    KSTEP(4, 6, 1) KSTEP(5, 6, 1) KSTEP(6, 6, 1) KSTEP(7, 6, 1)
    EPILOG();
    bm += 128;

    // ---- middle tiles: previous epilogue's E stores sit between slot(t,5)
    // and slot(t,6) in vmcnt age order -> kt0..5 allow 6+E, kt6..7 back to 6.
    for (int tt = 1; tt < NT - 1; ++tt) {
        KSTEP(0, 6 + E, 1) KSTEP(1, 6 + E, 1) KSTEP(2, 6 + E, 1) KSTEP(3, 6 + E, 1)
        KSTEP(4, 6 + E, 1) KSTEP(5, 6 + E, 1) KSTEP(6, 6, 1)     KSTEP(7, 6, 1)
        EPILOG();
        bm += 128;
    }

    // ---- last tile: staging stops after kt1; tail counts shrink
    KSTEP(0, 6 + E, 1) KSTEP(1, 6 + E, 1) KSTEP(2, 5 + E, 0) KSTEP(3, 4 + E, 0)
    KSTEP(4, 3 + E, 0) KSTEP(5, 2 + E, 0) KSTEP(6, 1, 0)     KSTEP(7, 0, 0)
    EPILOG();

#undef KSTEP
#undef EPILOG
}

// ---------------------------------------------------------------- edge attention
// Proven kernel, byte-identical (compiler software-pipelines the chunk loop;
// 1-wave blocks retire independently; deg<=16 weights in-register).
__global__ __launch_bounds__(64) void edge_attn_k(const ushort* __restrict__ qp,
                                                  const ushort* __restrict__ kp,
                                                  const float* __restrict__ bias,
                                                  const int* __restrict__ src,
                                                  const int* __restrict__ row_lo,
                                                  ushort* __restrict__ ao,
                                                  float* __restrict__ simw) {
    const int q    = blockIdx.x;
    const int lane = threadIdx.x;
    const int lo = row_lo[q];
    const int hi = row_lo[q + 1];
    const int deg = hi - lo;
    const float SC2 = SCL * LOG2E;

    ushort4 qu = *(const ushort4*)(qp + (size_t)q * CD + (lane << 2));
    float4 qv = {b2f(qu.x) * SC2, b2f(qu.y) * SC2, b2f(qu.z) * SC2, b2f(qu.w) * SC2};
    float4 acc = {0.f, 0.f, 0.f, 0.f};
    float m = -INFINITY, s = 0.f;
    float wval0 = 0.f, wval1 = 0.f;      // chunk-0 / chunk-1 transposed sims

    for (int base = lo; base < hi; base += 8) {
        const int cnum = (base - lo) >> 3;
        // ---- load phase: 1 src chunk + 1 bias chunk + up to 8 kp rows
        int sv = 0;
        if (lane < 8 && base + lane < hi) sv = src[base + lane];
        float bch = 0.f;
        if (lane < (hi - base) * 8) bch = bias[(size_t)base * NH + lane] * SC2;
        ushort4 ku[8];
        #pragma unroll
        for (int i = 0; i < 8; ++i) {
            if (base + i < hi) {
                int sidx = __shfl(sv, i);
                ku[i] = *(const ushort4*)(kp + (size_t)sidx * CD + (lane << 2));
            }
        }
        // ---- per-edge compute (online softmax, log2 domain)
        #pragma unroll
        for (int i = 0; i < 8; ++i) {
            if (base + i < hi) {
                float4 kv = {b2f(ku[i].x), b2f(ku[i].y), b2f(ku[i].z), b2f(ku[i].w)};
                float d = qv.x * kv.x + qv.y * kv.y + qv.z * kv.z + qv.w * kv.w;
                d += __shfl_xor(d, 1);
                d += __shfl_xor(d, 2);
                d += __shfl_xor(d, 4);
                float bvi = __shfl(bch, (i << 3) + (lane >> 3));
                float sim = d + bvi;                       // log2 domain
                float tw = __shfl(sim, (lane & 7) << 3);   // capture for weights output
                bool mine = ((lane >> 3) == i);
                if (deg <= 16) {
                    if (cnum == 0) wval0 = mine ? tw : wval0;
                    else           wval1 = mine ? tw : wval1;
                } else {
                    wval0 = mine ? tw : wval0;             // rolling (staged per chunk)
                }
                float mnew  = fmaxf(m, sim);
                float scale = fexp2(m - mnew);             // first edge: exp2(-inf)=0
                float ex    = fexp2(sim - mnew);
                s = s * scale + ex;
                acc.x = acc.x * scale + ex * kv.x;
                acc.y = acc.y * scale + ex * kv.y;
                acc.z = acc.z * scale + ex * kv.z;
                acc.w = acc.w * scale + ex * kv.w;
                m = mnew;
            }
        }
        // ---- stage raw (log2) sims only for deg>16 queries (rare)
        if (deg > 16) {
            int lim = hi - base; if (lim > 8) lim = 8;
            if (lane < lim * 8) simw[(size_t)base * NH + lane] = wval0;
        }
    }

    float ws  = s + 1e-8f;
    float inv = 1.0f / ws;
    ushort4 o;
    o.x = f2bf(acc.x * inv);
    o.y = f2bf(acc.y * inv);
    o.z = f2bf(acc.z * inv);
    o.w = f2bf(acc.w * inv);
    *(ushort4*)(ao + (size_t)q * CD + (lane << 2)) = o;

    if (deg > 0) {
        const float mm = __shfl(m,   (lane & 7) << 3);     // state of head lane&7
        const float ii = __shfl(inv, (lane & 7) << 3);
        if (deg <= 8) {
            if (lane < deg * 8)
                simw[(size_t)lo * NH + lane] = fexp2(wval0 - mm) * ii;
        } else if (deg <= 16) {
            simw[(size_t)lo * NH + lane] = fexp2(wval0 - mm) * ii;          // edges lo..lo+7
            if (lane < (deg - 8) * 8)
                simw[(size_t)(lo + 8) * NH + lane] = fexp2(wval1 - mm) * ii; // edges lo+8..
        } else {
            asm volatile("s_waitcnt vmcnt(0)" ::: "memory");   // drain sim stores
            for (int i = lane; i < deg * 8; i += 64) {
                size_t idx = (size_t)lo * NH + i;          // head = i&7 = lane&7
                float v = simw[idx];
                simw[idx] = fexp2(v - mm) * ii;
            }
        }
    }
}

// ---------------------------------------------------------------- launch
extern "C" void kernel_launch(void* const* d_in, const int* in_sizes, int n_in,
                              void* d_out, int out_size, void* d_ws, size_t ws_size,
                              hipStream_t stream) {
    const float* q    = (const float*)d_in[0];
    const float* k    = (const float*)d_in[1];
    const float* bias = (const float*)d_in[2];
    const float* lnw  = (const float*)d_in[3];
    const float* lnb  = (const float*)d_in[4];
    const float* wq   = (const float*)d_in[5];
    const float* bq   = (const float*)d_in[6];
    const float* wk   = (const float*)d_in[7];
    const float* bk   = (const float*)d_in[8];
    const float* wo   = (const float*)d_in[9];
    const float* bo   = (const float*)d_in[10];
    const int*   src  = (const int*)d_in[11];
    const int*   dst  = (const int*)d_in[12];

    float* out_m = (float*)d_out;                   // [QN][CD] fp32
    float* out_w = out_m + (size_t)QN * CD;         // [NE][NH] fp32 (weights)

    ushort* qn_b = (ushort*)d_ws;                   // [QN][CD]  LN(q) bf16 -> reused as attn_out
    ushort* qp_b = qn_b + (size_t)QN * CD;          // [QN][CD]  qp bf16
    ushort* kp_b = qp_b + (size_t)QN * CD;          // [KVN][CD] kp bf16
    ushort* wb   = kp_b + (size_t)KVN * CD;         // 3 x [256*256] bf16 weights
    int*    rowlo = (int*)(wb + 3 * 65536);         // [QN+1]

    // kb (k converted to bf16) lives in the out_m region: it is consumed by
    // gemm2<0> and out_m is only written by the final gemm2<1>.
    ushort* kb = (ushort*)d_out;                    // [KVN][CD] bf16 (32 MB of 64)

    prep_k<<<dim3(LNB + 192 + RLB + LNB), dim3(256), 0, stream>>>(
        q, k, lnw, lnb, wq, wk, wo, dst, qn_b, kb, wb, rowlo);

    // z=0: qp = LN(q)@wq ; z=1: kp = kb@wk   (both bf16, identical blocks)
    gemm2_k<0, 8><<<dim3(64, 2, 2), dim3(512), 0, stream>>>(
        qn_b, kb, wb, wb + 65536, bq, bk, nullptr, qp_b, kp_b);

    edge_attn_k<<<dim3(QN), dim3(64), 0, stream>>>(
        qp_b, kp_b, bias, src, rowlo, qn_b /*ao*/, out_w);

    // out = attn_out@wo + bo + q
    gemm2_k<1, 4><<<dim3(128, 2, 1), dim3(512), 0, stream>>>(
        qn_b, qn_b, wb + 131072, wb + 131072, bo, bo, q, out_m, out_m);
}